// Round 1
// baseline (276.155 us; speedup 1.0000x reference)
//
#include <hip/hip_runtime.h>
#include <cstddef>

// QuadTree attention, 3 levels. B=4, C=128, NHEAD=8, d=16.
// Level grids: 16x16 (S=256), 32x32 (S=1024), 64x64 (S=4096).
// TOPKS = (16, 8, 8). Level 2 is final: no top-k needed, fuses output.
//
// Workspace layout (floats):
//   tscore0: 4*256*16*8   = 131072   [b,l,kp,n]
//   tpos0  : 131072 (int)            [b,l,kp,n]  coarse key index s in [0,256)
//   msg0   : 4*256*8*16   = 131072   [b,l,n,d]
//   tscore1: 4*1024*8*8   = 262144   [b,l1,kp,n]
//   tpos1  : 262144 (int)            [b,l1,kp,n] fine key index g in [0,1024)
//   msg1   : 4*1024*8*16  = 524288   [b,l1,n,d]
// total 1,441,792 floats = 5.77 MB

__device__ __forceinline__ float groupmax4(float x) {
    x = fmaxf(x, __shfl_xor(x, 1));
    x = fmaxf(x, __shfl_xor(x, 2));
    return x;
}
__device__ __forceinline__ float groupsum4(float x) {
    x += __shfl_xor(x, 1);
    x += __shfl_xor(x, 2);
    return x;
}

// ---------------- Level 0 (coarse, 16x16) ----------------
// one wave per (b, l, n). lane owns 4 keys: s = lane*4 .. lane*4+3.
__global__ __launch_bounds__(256) void k_lvl0(
    const float* __restrict__ q, const float* __restrict__ k, const float* __restrict__ v,
    float* __restrict__ tscore0, int* __restrict__ tpos0, float* __restrict__ msg0)
{
    const int tid  = threadIdx.x;
    const int lane = tid & 63;
    const int wid  = tid >> 6;
    const int l = blockIdx.x * 4 + wid;   // 0..255
    const int n = blockIdx.y;             // 0..7
    const int b = blockIdx.z;             // 0..3
    const int S = 256;

    __shared__ float p_lds[4][256];

    const float* qb = q + ((size_t)(b*128 + n*16))*S + l;
    const float* kb = k + ((size_t)(b*128 + n*16))*S + lane*4;

    float qreg[16];
    #pragma unroll
    for (int dd = 0; dd < 16; ++dd) qreg[dd] = qb[(size_t)dd*S];

    float sc[4] = {0.f,0.f,0.f,0.f};
    #pragma unroll
    for (int dd = 0; dd < 16; ++dd) {
        float4 kv = *(const float4*)(kb + (size_t)dd*S);
        sc[0] = fmaf(qreg[dd], kv.x, sc[0]);
        sc[1] = fmaf(qreg[dd], kv.y, sc[1]);
        sc[2] = fmaf(qreg[dd], kv.z, sc[2]);
        sc[3] = fmaf(qreg[dd], kv.w, sc[3]);
    }
    #pragma unroll
    for (int j = 0; j < 4; ++j) sc[j] *= 0.25f;  // 1/sqrt(16)

    // softmax over all 256 keys
    float m = fmaxf(fmaxf(sc[0], sc[1]), fmaxf(sc[2], sc[3]));
    #pragma unroll
    for (int off = 1; off < 64; off <<= 1) m = fmaxf(m, __shfl_xor(m, off));
    float p[4];
    float ssum = 0.f;
    #pragma unroll
    for (int j = 0; j < 4; ++j) { p[j] = expf(sc[j] - m); ssum += p[j]; }
    #pragma unroll
    for (int off = 1; off < 64; off <<= 1) ssum += __shfl_xor(ssum, off);
    const float inv = 1.f / ssum;
    #pragma unroll
    for (int j = 0; j < 4; ++j) p[j] *= inv;

    // top-16 extraction; winners get zeroed (this is exactly the mask for msg0)
    const size_t tbase = (size_t)(b*256 + l)*128 + n;   // ((b*256+l)*16+it)*8+n
    #pragma unroll 1
    for (int it = 0; it < 16; ++it) {
        float lv = p[0]; int li = 0;
        if (p[1] > lv) { lv = p[1]; li = 1; }
        if (p[2] > lv) { lv = p[2]; li = 2; }
        if (p[3] > lv) { lv = p[3]; li = 3; }
        int gi = (lane << 2) | li;
        #pragma unroll
        for (int off = 1; off < 64; off <<= 1) {
            float ov = __shfl_xor(lv, off);
            int   oi = __shfl_xor(gi, off);
            if (ov > lv || (ov == lv && oi < gi)) { lv = ov; gi = oi; }
        }
        if ((gi >> 2) == lane) p[gi & 3] = 0.f;
        if (lane == it) {
            tscore0[tbase + (size_t)it*8] = lv;
            tpos0  [tbase + (size_t)it*8] = gi;
        }
    }

    *(float4*)&p_lds[wid][lane*4] = make_float4(p[0], p[1], p[2], p[3]);
    __syncthreads();

    // msg0[b,l,n,dd] = sum_s p_masked[s] * V[b,s,n,dd]
    // lane <-> (chunk = lane>>4 over s, dd = lane&15); reduce over 4 chunks.
    const int dd = lane & 15, chunk = lane >> 4;
    const float* vb = v + ((size_t)(b*128 + n*16 + dd))*S + chunk*64;
    float acc = 0.f;
    #pragma unroll
    for (int j = 0; j < 64; j += 4) {
        float4 vv = *(const float4*)(vb + j);
        acc = fmaf(p_lds[wid][chunk*64+j+0], vv.x, acc);
        acc = fmaf(p_lds[wid][chunk*64+j+1], vv.y, acc);
        acc = fmaf(p_lds[wid][chunk*64+j+2], vv.z, acc);
        acc = fmaf(p_lds[wid][chunk*64+j+3], vv.w, acc);
    }
    acc += __shfl_xor(acc, 16);
    acc += __shfl_xor(acc, 32);
    if (lane < 16)
        msg0[(((size_t)b*256 + l)*8 + n)*16 + dd] = acc;
}

// ---------------- Level 1 (fine, 32x32) ----------------
// one wave per (b, L, n), L on 16x16 coarse grid. lane <-> key (kp=lane>>2 parent, ci=lane&3 child).
__global__ __launch_bounds__(256) void k_lvl1(
    const float* __restrict__ q, const float* __restrict__ k, const float* __restrict__ v,
    const float* __restrict__ tscore0, const int* __restrict__ tpos0,
    float* __restrict__ tscore1, int* __restrict__ tpos1, float* __restrict__ msg1)
{
    const int tid = threadIdx.x, lane = tid & 63, wid = tid >> 6;
    const int L = blockIdx.x;              // 0..255
    const int n = blockIdx.y * 4 + wid;    // 0..7
    const int b = blockIdx.z;
    const int S = 1024;

    __shared__ float pl[4][4][64];   // [wave][t][key]
    __shared__ float vl[4][64][17];  // [wave][key][dd] (+1 pad)

    const int kp = lane >> 2, ci = lane & 3;
    const size_t pb = (((size_t)b*256 + L)*16 + kp)*8 + n;
    const int   s      = tpos0[pb];
    const float pscore = tscore0[pb];
    // child (x=ci>>1, y=ci&1) of coarse key s=(p0,p1) on 32-wide fine grid
    const int g = (((s >> 4)*2 + (ci >> 1)) << 5) + ((s & 15)*2 + (ci & 1));

    const float* kb = k + ((size_t)(b*128 + n*16))*S + g;
    const float* vb = v + ((size_t)(b*128 + n*16))*S + g;
    float kreg[16], vreg[16];
    #pragma unroll
    for (int dd = 0; dd < 16; ++dd) { kreg[dd] = kb[(size_t)dd*S]; vreg[dd] = vb[(size_t)dd*S]; }

    const int H = L >> 4, W = L & 15;
    const float* qhead = q + ((size_t)(b*128 + n*16))*S;

    float p[4];
    #pragma unroll
    for (int t = 0; t < 4; ++t) {
        const int qg = ((2*H + (t>>1)) << 5) + 2*W + (t&1);
        float sc = 0.f;
        #pragma unroll
        for (int dd = 0; dd < 16; ++dd) sc = fmaf(qhead[(size_t)dd*S + qg], kreg[dd], sc);
        sc *= 0.25f;
        const float mm = groupmax4(sc);          // softmax over 4 children of same parent
        const float e  = expf(sc - mm);
        const float su = groupsum4(e);
        p[t] = (e / su) * pscore;                // multiply by parent score BEFORE topk (matches ref)
    }

    // per query t: top-8 of 64 (store at quad_to_grid position), zero winners (mask for msg)
    #pragma unroll 1
    for (int t = 0; t < 4; ++t) {
        float pv = p[t];
        const int l1 = ((2*H + (t>>1)) << 5) + 2*W + (t&1);
        const size_t obase = (size_t)(b*1024 + l1)*64 + n;  // ((b*1024+l1)*8+it)*8+n
        #pragma unroll 1
        for (int it = 0; it < 8; ++it) {
            float lv = pv; int li = lane; int lg = g;
            #pragma unroll
            for (int off = 1; off < 64; off <<= 1) {
                float ov = __shfl_xor(lv, off);
                int   oi = __shfl_xor(li, off);
                int   og = __shfl_xor(lg, off);
                if (ov > lv || (ov == lv && oi < li)) { lv = ov; li = oi; lg = og; }
            }
            if (li == lane) pv = 0.f;
            if (lane == it) {
                tscore1[obase + (size_t)it*8] = lv;
                tpos1  [obase + (size_t)it*8] = lg;
            }
        }
        pl[wid][t][lane] = pv;
    }
    #pragma unroll
    for (int dd = 0; dd < 16; ++dd) vl[wid][lane][dd] = vreg[dd];
    __syncthreads();

    // msg: lane <-> (t = lane>>4, dd = lane&15); dot over 64 keys
    const int t = lane >> 4, dd = lane & 15;
    float acc = 0.f;
    #pragma unroll
    for (int kk = 0; kk < 64; ++kk)
        acc = fmaf(pl[wid][t][kk], vl[wid][kk][dd], acc);
    const int l1 = ((2*H + (t>>1)) << 5) + 2*W + (t&1);
    msg1[(((size_t)b*1024 + l1)*8 + n)*16 + dd] = acc;
}

// ---------------- Level 2 (final, 64x64) + fusion ----------------
// one wave per (b, L, n), L on 32x32 grid. lanes 0..31 <-> 32 keys (8 parents x 4 children).
// No top-k (final). Writes d_out directly: msg2 + upsampled msg1 + msg0.
__global__ __launch_bounds__(256) void k_lvl2(
    const float* __restrict__ q, const float* __restrict__ k, const float* __restrict__ v,
    const float* __restrict__ tscore1, const int* __restrict__ tpos1,
    const float* __restrict__ msg0, const float* __restrict__ msg1,
    float* __restrict__ out)
{
    const int tid = threadIdx.x, lane = tid & 63, wid = tid >> 6;
    const int L = blockIdx.x;              // 0..1023
    const int n = blockIdx.y * 4 + wid;    // 0..7
    const int b = blockIdx.z;
    const int S = 4096;

    __shared__ float pl[4][4][32];
    __shared__ float vl[4][32][17];

    const bool active = lane < 32;
    const int kp = lane >> 2, ci = lane & 3;
    float pscore = 0.f; int g = 0;
    if (active) {
        const size_t pb = (((size_t)b*1024 + L)*8 + kp)*8 + n;
        const int g1 = tpos1[pb];
        pscore = tscore1[pb];
        g = (((g1 >> 5)*2 + (ci >> 1)) << 6) + ((g1 & 31)*2 + (ci & 1));
    }

    const float* kb = k + ((size_t)(b*128 + n*16))*S + g;
    const float* vb = v + ((size_t)(b*128 + n*16))*S + g;
    float kreg[16], vreg[16];
    #pragma unroll
    for (int dd = 0; dd < 16; ++dd) { kreg[dd] = kb[(size_t)dd*S]; vreg[dd] = vb[(size_t)dd*S]; }

    const int H = L >> 5, W = L & 31;
    const float* qhead = q + ((size_t)(b*128 + n*16))*S;

    float p[4];
    #pragma unroll
    for (int t = 0; t < 4; ++t) {
        const int qg = ((2*H + (t>>1)) << 6) + 2*W + (t&1);
        float sc = 0.f;
        #pragma unroll
        for (int dd = 0; dd < 16; ++dd) sc = fmaf(qhead[(size_t)dd*S + qg], kreg[dd], sc);
        sc *= 0.25f;
        const float mm = groupmax4(sc);
        const float e  = expf(sc - mm);
        const float su = groupsum4(e);
        p[t] = active ? (e / su) * pscore : 0.f;
    }

    if (active) {
        #pragma unroll
        for (int t = 0; t < 4; ++t) pl[wid][t][lane] = p[t];
        #pragma unroll
        for (int dd = 0; dd < 16; ++dd) vl[wid][lane][dd] = vreg[dd];
    }
    __syncthreads();

    // lane <-> (t = lane>>4, dd = lane&15); full (unmasked) sum over 32 keys
    const int t = lane >> 4, dd = lane & 15;
    float acc = 0.f;
    #pragma unroll
    for (int kk = 0; kk < 32; ++kk)
        acc = fmaf(pl[wid][t][kk], vl[wid][kk][dd], acc);

    const int yy = 2*H + (t>>1), xx = 2*W + (t&1);
    const int l0 = (H >> 1)*16 + (W >> 1);   // coarse 16x16 cell containing (yy,xx)
    const float r = acc
        + msg1[(((size_t)b*1024 + L)*8 + n)*16 + dd]
        + msg0[(((size_t)b*256 + l0)*8 + n)*16 + dd];
    out[((size_t)(b*128 + n*16 + dd)*64 + yy)*64 + xx] = r;
}

extern "C" void kernel_launch(void* const* d_in, const int* in_sizes, int n_in,
                              void* d_out, int out_size, void* d_ws, size_t ws_size,
                              hipStream_t stream)
{
    const float* q0 = (const float*)d_in[0];
    const float* k0 = (const float*)d_in[1];
    const float* v0 = (const float*)d_in[2];
    const float* q1 = (const float*)d_in[3];
    const float* k1 = (const float*)d_in[4];
    const float* v1 = (const float*)d_in[5];
    const float* q2 = (const float*)d_in[6];
    const float* k2 = (const float*)d_in[7];
    const float* v2 = (const float*)d_in[8];

    float* ws = (float*)d_ws;
    float* tscore0 = ws;                       // 131072 floats
    int*   tpos0   = (int*)(ws + 131072);      // 131072 ints
    float* msg0    = ws + 262144;              // 131072 floats
    float* tscore1 = ws + 393216;              // 262144 floats
    int*   tpos1   = (int*)(ws + 655360);      // 262144 ints
    float* msg1    = ws + 917504;              // 524288 floats

    k_lvl0<<<dim3(64,   8, 4), 256, 0, stream>>>(q0, k0, v0, tscore0, tpos0, msg0);
    k_lvl1<<<dim3(256,  2, 4), 256, 0, stream>>>(q1, k1, v1, tscore0, tpos0, tscore1, tpos1, msg1);
    k_lvl2<<<dim3(1024, 2, 4), 256, 0, stream>>>(q2, k2, v2, tscore1, tpos1, msg0, msg1, (float*)d_out);
}

// Round 2
// 221.945 us; speedup vs baseline: 1.2442x; 1.2442x over previous
//
#include <hip/hip_runtime.h>
#include <cstddef>

// QuadTree attention, 3 levels. B=4, C=128, NHEAD=8, d=16.
// Level grids: 16x16 (S=256), 32x32 (S=1024), 64x64 (S=4096).
// TOPKS = (16, 8, 8). Level 2 is final: no top-k needed, fuses output.
//
// R1 change: token-major pre-transpose of q/k/v for levels 1,2 so the
// per-key gather is 64B contiguous (1 line, fully used) instead of 16
// scattered 4B dwords 16KB apart. Output written token-major, then
// transposed back coalesced.

union F16 { float4 v[4]; float f[16]; };

__device__ __forceinline__ float groupmax4(float x) {
    x = fmaxf(x, __shfl_xor(x, 1));
    x = fmaxf(x, __shfl_xor(x, 2));
    return x;
}
__device__ __forceinline__ float groupsum4(float x) {
    x += __shfl_xor(x, 1);
    x += __shfl_xor(x, 2);
    return x;
}

// ---------------- Transpose: [R][C] -> [C][R] per batch, up to 3 tensors ----
// grid: (C/32, nTensors*(R/32), B). rtShift = log2(R/32).
__global__ __launch_bounds__(256) void k_xpose3(
    const float* __restrict__ in0, const float* __restrict__ in1, const float* __restrict__ in2,
    float* __restrict__ o0, float* __restrict__ o1, float* __restrict__ o2,
    int R, int C, int rtShift)
{
    __shared__ float tile[32][33];
    const int which = blockIdx.y >> rtShift;
    const int rt    = blockIdx.y & ((1 << rtShift) - 1);
    const float* in = which == 0 ? in0 : (which == 1 ? in1 : in2);
    float*      out = which == 0 ? o0  : (which == 1 ? o1  : o2);
    const size_t boff = (size_t)blockIdx.z * R * C;
    in += boff; out += boff;
    const int tx = threadIdx.x & 31, ty = threadIdx.x >> 5;
    const int r0 = rt * 32, c0 = blockIdx.x * 32;
    #pragma unroll
    for (int j = 0; j < 4; ++j)
        tile[ty + 8*j][tx] = in[(size_t)(r0 + ty + 8*j) * C + c0 + tx];
    __syncthreads();
    #pragma unroll
    for (int j = 0; j < 4; ++j)
        out[(size_t)(c0 + ty + 8*j) * R + r0 + tx] = tile[tx][ty + 8*j];
}

// ---------------- Level 0 (coarse, 16x16) ----------------
// one wave per (b, l, n). lane owns 4 keys: s = lane*4 .. lane*4+3.
// K/V access is already perfectly coalesced in [b,c,h,w]; unchanged from R0.
__global__ __launch_bounds__(256) void k_lvl0(
    const float* __restrict__ q, const float* __restrict__ k, const float* __restrict__ v,
    float* __restrict__ tscore0, int* __restrict__ tpos0, float* __restrict__ msg0)
{
    const int tid  = threadIdx.x;
    const int lane = tid & 63;
    const int wid  = tid >> 6;
    const int l = blockIdx.x * 4 + wid;   // 0..255
    const int n = blockIdx.y;             // 0..7
    const int b = blockIdx.z;             // 0..3
    const int S = 256;

    __shared__ float p_lds[4][256];

    const float* qb = q + ((size_t)(b*128 + n*16))*S + l;
    const float* kb = k + ((size_t)(b*128 + n*16))*S + lane*4;

    float qreg[16];
    #pragma unroll
    for (int dd = 0; dd < 16; ++dd) qreg[dd] = qb[(size_t)dd*S];

    float sc[4] = {0.f,0.f,0.f,0.f};
    #pragma unroll
    for (int dd = 0; dd < 16; ++dd) {
        float4 kv = *(const float4*)(kb + (size_t)dd*S);
        sc[0] = fmaf(qreg[dd], kv.x, sc[0]);
        sc[1] = fmaf(qreg[dd], kv.y, sc[1]);
        sc[2] = fmaf(qreg[dd], kv.z, sc[2]);
        sc[3] = fmaf(qreg[dd], kv.w, sc[3]);
    }
    #pragma unroll
    for (int j = 0; j < 4; ++j) sc[j] *= 0.25f;  // 1/sqrt(16)

    float m = fmaxf(fmaxf(sc[0], sc[1]), fmaxf(sc[2], sc[3]));
    #pragma unroll
    for (int off = 1; off < 64; off <<= 1) m = fmaxf(m, __shfl_xor(m, off));
    float p[4];
    float ssum = 0.f;
    #pragma unroll
    for (int j = 0; j < 4; ++j) { p[j] = expf(sc[j] - m); ssum += p[j]; }
    #pragma unroll
    for (int off = 1; off < 64; off <<= 1) ssum += __shfl_xor(ssum, off);
    const float inv = 1.f / ssum;
    #pragma unroll
    for (int j = 0; j < 4; ++j) p[j] *= inv;

    const size_t tbase = (size_t)(b*256 + l)*128 + n;   // ((b*256+l)*16+it)*8+n
    #pragma unroll 1
    for (int it = 0; it < 16; ++it) {
        float lv = p[0]; int li = 0;
        if (p[1] > lv) { lv = p[1]; li = 1; }
        if (p[2] > lv) { lv = p[2]; li = 2; }
        if (p[3] > lv) { lv = p[3]; li = 3; }
        int gi = (lane << 2) | li;
        #pragma unroll
        for (int off = 1; off < 64; off <<= 1) {
            float ov = __shfl_xor(lv, off);
            int   oi = __shfl_xor(gi, off);
            if (ov > lv || (ov == lv && oi < gi)) { lv = ov; gi = oi; }
        }
        if ((gi >> 2) == lane) p[gi & 3] = 0.f;
        if (lane == it) {
            tscore0[tbase + (size_t)it*8] = lv;
            tpos0  [tbase + (size_t)it*8] = gi;
        }
    }

    *(float4*)&p_lds[wid][lane*4] = make_float4(p[0], p[1], p[2], p[3]);
    __syncthreads();

    const int dd = lane & 15, chunk = lane >> 4;
    const float* vb = v + ((size_t)(b*128 + n*16 + dd))*S + chunk*64;
    float acc = 0.f;
    #pragma unroll
    for (int j = 0; j < 64; j += 4) {
        float4 vv = *(const float4*)(vb + j);
        acc = fmaf(p_lds[wid][chunk*64+j+0], vv.x, acc);
        acc = fmaf(p_lds[wid][chunk*64+j+1], vv.y, acc);
        acc = fmaf(p_lds[wid][chunk*64+j+2], vv.z, acc);
        acc = fmaf(p_lds[wid][chunk*64+j+3], vv.w, acc);
    }
    acc += __shfl_xor(acc, 16);
    acc += __shfl_xor(acc, 32);
    if (lane < 16)
        msg0[(((size_t)b*256 + l)*8 + n)*16 + dd] = acc;
}

// ---------------- Level 1 (fine, 32x32) ----------------
// one wave per (b, L, n), L on 16x16 coarse grid. lane <-> key.
// Token-major inputs: Qt/Kt/Vt = [b][1024][128].
__global__ __launch_bounds__(256) void k_lvl1(
    const float* __restrict__ Qt, const float* __restrict__ Kt, const float* __restrict__ Vt,
    const float* __restrict__ tscore0, const int* __restrict__ tpos0,
    float* __restrict__ tscore1, int* __restrict__ tpos1, float* __restrict__ msg1)
{
    const int tid = threadIdx.x, lane = tid & 63, wid = tid >> 6;
    const int L = blockIdx.x;              // 0..255
    const int n = blockIdx.y * 4 + wid;    // 0..7
    const int b = blockIdx.z;

    __shared__ float pl[4][4][64];   // [wave][t][key]
    __shared__ float vl[4][64][17];  // [wave][key][dd] (+1 pad)
    __shared__ float ql[4][4][16];   // [wave][t][dd]

    const int kp = lane >> 2, ci = lane & 3;
    const size_t pb = (((size_t)b*256 + L)*16 + kp)*8 + n;
    const int   s      = tpos0[pb];
    const float pscore = tscore0[pb];
    const int g = (((s >> 4)*2 + (ci >> 1)) << 5) + ((s & 15)*2 + (ci & 1));

    // gather: one lane = one key, 64B contiguous
    const float* kt = Kt + ((size_t)(b*1024 + g)*128 + n*16);
    const float* vt = Vt + ((size_t)(b*1024 + g)*128 + n*16);
    F16 kk, vv;
    #pragma unroll
    for (int i = 0; i < 4; ++i) { kk.v[i] = *(const float4*)(kt + i*4);
                                  vv.v[i] = *(const float4*)(vt + i*4); }

    const int H = L >> 4, W = L & 15;
    if (lane < 16) {
        const int t = lane >> 2;
        const int qtok = ((2*H + (t>>1)) << 5) + 2*W + (t&1);
        *(float4*)&ql[wid][t][(lane&3)*4] =
            *(const float4*)(Qt + ((size_t)(b*1024 + qtok)*128 + n*16 + (lane&3)*4));
    }
    #pragma unroll
    for (int dd = 0; dd < 16; ++dd) vl[wid][lane][dd] = vv.f[dd];
    __syncthreads();

    float p[4];
    #pragma unroll
    for (int t = 0; t < 4; ++t) {
        float sc = 0.f;
        #pragma unroll
        for (int i = 0; i < 16; ++i) sc = fmaf(ql[wid][t][i], kk.f[i], sc);
        sc *= 0.25f;
        const float mm = groupmax4(sc);
        const float e  = expf(sc - mm);
        const float su = groupsum4(e);
        p[t] = (e / su) * pscore;
    }

    #pragma unroll 1
    for (int t = 0; t < 4; ++t) {
        float pv = p[t];
        const int l1 = ((2*H + (t>>1)) << 5) + 2*W + (t&1);
        const size_t obase = (size_t)(b*1024 + l1)*64 + n;  // ((b*1024+l1)*8+it)*8+n
        #pragma unroll 1
        for (int it = 0; it < 8; ++it) {
            float lv = pv; int li = lane; int lg = g;
            #pragma unroll
            for (int off = 1; off < 64; off <<= 1) {
                float ov = __shfl_xor(lv, off);
                int   oi = __shfl_xor(li, off);
                int   og = __shfl_xor(lg, off);
                if (ov > lv || (ov == lv && oi < li)) { lv = ov; li = oi; lg = og; }
            }
            if (li == lane) pv = 0.f;
            if (lane == it) {
                tscore1[obase + (size_t)it*8] = lv;
                tpos1  [obase + (size_t)it*8] = lg;
            }
        }
        pl[wid][t][lane] = pv;
    }
    __syncthreads();

    const int t = lane >> 4, dd = lane & 15;
    float acc = 0.f;
    #pragma unroll
    for (int k2 = 0; k2 < 64; ++k2)
        acc = fmaf(pl[wid][t][k2], vl[wid][k2][dd], acc);
    const int l1 = ((2*H + (t>>1)) << 5) + 2*W + (t&1);
    msg1[(((size_t)b*1024 + l1)*8 + n)*16 + dd] = acc;
}

// ---------------- Level 2 (final, 64x64) + fusion ----------------
// one wave per (b, L, n), L on 32x32 grid. keys on lanes 0..31.
// Token-major inputs [b][4096][128]; writes token-major outT.
__global__ __launch_bounds__(256) void k_lvl2(
    const float* __restrict__ Qt, const float* __restrict__ Kt, const float* __restrict__ Vt,
    const float* __restrict__ tscore1, const int* __restrict__ tpos1,
    const float* __restrict__ msg0, const float* __restrict__ msg1,
    float* __restrict__ outT)
{
    const int tid = threadIdx.x, lane = tid & 63, wid = tid >> 6;
    const int L = blockIdx.x;              // 0..1023
    const int n = blockIdx.y * 4 + wid;    // 0..7
    const int b = blockIdx.z;

    __shared__ float pl[4][4][32];
    __shared__ float vl[4][32][17];
    __shared__ float ql[4][4][16];

    const bool active = lane < 32;
    const int kp = lane >> 2, ci = lane & 3;
    float pscore = 0.f; int g = 0;
    if (active) {
        const size_t pb = (((size_t)b*1024 + L)*8 + kp)*8 + n;
        const int g1 = tpos1[pb];
        pscore = tscore1[pb];
        g = (((g1 >> 5)*2 + (ci >> 1)) << 6) + ((g1 & 31)*2 + (ci & 1));
    }

    const float* kt = Kt + ((size_t)(b*4096 + g)*128 + n*16);
    const float* vt = Vt + ((size_t)(b*4096 + g)*128 + n*16);
    F16 kk, vv;
    #pragma unroll
    for (int i = 0; i < 4; ++i) { kk.v[i] = *(const float4*)(kt + i*4);
                                  vv.v[i] = *(const float4*)(vt + i*4); }

    const int H = L >> 5, W = L & 31;
    if (lane < 16) {
        const int t = lane >> 2;
        const int qtok = ((2*H + (t>>1)) << 6) + 2*W + (t&1);
        *(float4*)&ql[wid][t][(lane&3)*4] =
            *(const float4*)(Qt + ((size_t)(b*4096 + qtok)*128 + n*16 + (lane&3)*4));
    }
    if (active) {
        #pragma unroll
        for (int dd = 0; dd < 16; ++dd) vl[wid][lane][dd] = vv.f[dd];
    }
    __syncthreads();

    float p[4];
    #pragma unroll
    for (int t = 0; t < 4; ++t) {
        float sc = 0.f;
        #pragma unroll
        for (int i = 0; i < 16; ++i) sc = fmaf(ql[wid][t][i], kk.f[i], sc);
        sc *= 0.25f;
        const float mm = groupmax4(sc);
        const float e  = expf(sc - mm);
        const float su = groupsum4(e);
        p[t] = active ? (e / su) * pscore : 0.f;
    }
    if (active) {
        #pragma unroll
        for (int t = 0; t < 4; ++t) pl[wid][t][lane] = p[t];
    }
    __syncthreads();

    const int t = lane >> 4, dd = lane & 15;
    float acc = 0.f;
    #pragma unroll
    for (int k2 = 0; k2 < 32; ++k2)
        acc = fmaf(pl[wid][t][k2], vl[wid][k2][dd], acc);

    const int qtok = ((2*H + (t>>1)) << 6) + 2*W + (t&1);
    const int l0 = (H >> 1)*16 + (W >> 1);
    const float r = acc
        + msg1[(((size_t)b*1024 + L)*8 + n)*16 + dd]
        + msg0[(((size_t)b*256 + l0)*8 + n)*16 + dd];
    outT[((size_t)b*4096 + qtok)*128 + n*16 + dd] = r;
}

extern "C" void kernel_launch(void* const* d_in, const int* in_sizes, int n_in,
                              void* d_out, int out_size, void* d_ws, size_t ws_size,
                              hipStream_t stream)
{
    const float* q0 = (const float*)d_in[0];
    const float* k0 = (const float*)d_in[1];
    const float* v0 = (const float*)d_in[2];
    const float* q1 = (const float*)d_in[3];
    const float* k1 = (const float*)d_in[4];
    const float* v1 = (const float*)d_in[5];
    const float* q2 = (const float*)d_in[6];
    const float* k2 = (const float*)d_in[7];
    const float* v2 = (const float*)d_in[8];

    float* ws = (float*)d_ws;
    float* tscore0 = ws;                        // 131072
    int*   tpos0   = (int*)(ws + 131072);       // 131072
    float* msg0    = ws + 262144;               // 131072
    float* tscore1 = ws + 393216;               // 262144
    int*   tpos1   = (int*)(ws + 655360);       // 262144
    float* msg1    = ws + 917504;               // 524288
    float* q1t     = ws + 1441792;              // 524288
    float* k1t     = ws + 1966080;              // 524288
    float* v1t     = ws + 2490368;              // 524288
    float* q2t     = ws + 3014656;              // 2097152
    float* k2t     = ws + 5111808;              // 2097152
    float* v2t     = ws + 7208960;              // 2097152
    float* outT    = ws + 9306112;              // 2097152

    // token-major transposes: [128][S] -> [S][128]
    k_xpose3<<<dim3(32,  12, 4), 256, 0, stream>>>(q1, k1, v1, q1t, k1t, v1t, 128, 1024, 2);
    k_xpose3<<<dim3(128, 12, 4), 256, 0, stream>>>(q2, k2, v2, q2t, k2t, v2t, 128, 4096, 2);

    k_lvl0<<<dim3(64,   8, 4), 256, 0, stream>>>(q0, k0, v0, tscore0, tpos0, msg0);
    k_lvl1<<<dim3(256,  2, 4), 256, 0, stream>>>(q1t, k1t, v1t, tscore0, tpos0, tscore1, tpos1, msg1);
    k_lvl2<<<dim3(1024, 2, 4), 256, 0, stream>>>(q2t, k2t, v2t, tscore1, tpos1, msg0, msg1, outT);

    // outT [4096][128] -> out [128][4096]
    k_xpose3<<<dim3(4, 128, 4), 256, 0, stream>>>(outT, outT, outT,
                                                  (float*)d_out, (float*)d_out, (float*)d_out,
                                                  4096, 128, 7);
}

// Round 3
// 168.999 us; speedup vs baseline: 1.6341x; 1.3133x over previous
//
#include <hip/hip_runtime.h>
#include <cstddef>

// QuadTree attention, 3 levels. B=4, C=128, NHEAD=8, d=16.
// Level grids: 16x16 (S=256), 32x32 (S=1024), 64x64 (S=4096).
// TOPKS = (16, 8, 8). Level 2 is final: no top-k needed, fuses output.
//
// R3: all cross-lane selection via DPP row_ror (16-lane groups, VALU pipe,
// zero LDS-pipe shuffles); V gathered directly from global (token-major)
// in the msg phase; masked p via one b128 LDS round-trip per query.

#define DPP_QUAD_X1 0xB1   // quad_perm [1,0,3,2]  == xor 1
#define DPP_QUAD_X2 0x4E   // quad_perm [2,3,0,1]  == xor 2
#define DPP_ROR_1   0x121
#define DPP_ROR_2   0x122
#define DPP_ROR_4   0x124
#define DPP_ROR_8   0x128

template<int C>
__device__ __forceinline__ int dpp_i(int x) {
    return __builtin_amdgcn_mov_dpp(x, C, 0xF, 0xF, true);
}
template<int C>
__device__ __forceinline__ float dpp_f(float x) {
    return __int_as_float(__builtin_amdgcn_mov_dpp(__float_as_int(x), C, 0xF, 0xF, true));
}

// max / sum over the 16 lanes of a row (cyclic-window rotation reduce)
__device__ __forceinline__ float rowmax16(float x) {
    x = fmaxf(x, dpp_f<DPP_ROR_1>(x));
    x = fmaxf(x, dpp_f<DPP_ROR_2>(x));
    x = fmaxf(x, dpp_f<DPP_ROR_4>(x));
    x = fmaxf(x, dpp_f<DPP_ROR_8>(x));
    return x;
}
__device__ __forceinline__ float rowsum16(float x) {
    x += dpp_f<DPP_ROR_1>(x);
    x += dpp_f<DPP_ROR_2>(x);
    x += dpp_f<DPP_ROR_4>(x);
    x += dpp_f<DPP_ROR_8>(x);
    return x;
}
// softmax over 4 children (lane quads) — bit-identical to __shfl_xor 1,2
__device__ __forceinline__ float quadmax4(float x) {
    x = fmaxf(x, dpp_f<DPP_QUAD_X1>(x));
    x = fmaxf(x, dpp_f<DPP_QUAD_X2>(x));
    return x;
}
__device__ __forceinline__ float quadsum4(float x) {
    x += dpp_f<DPP_QUAD_X1>(x);
    x += dpp_f<DPP_QUAD_X2>(x);
    return x;
}
// argmax (max value, tie -> lower slot) over 16-lane row; all lanes get result
template<int C>
__device__ __forceinline__ void amax_step(float& v, int& s) {
    float ov = dpp_f<C>(v);
    int   os = dpp_i<C>(s);
    const bool take = (ov > v) || (ov == v && os < s);
    v = take ? ov : v;
    s = take ? os : s;
}
__device__ __forceinline__ void amax16(float& v, int& s) {
    amax_step<DPP_ROR_1>(v, s);
    amax_step<DPP_ROR_2>(v, s);
    amax_step<DPP_ROR_4>(v, s);
    amax_step<DPP_ROR_8>(v, s);
}

// ---------------- Transpose: [R][C] -> [C][R] per batch, up to 3 tensors ----
__global__ __launch_bounds__(256) void k_xpose3(
    const float* __restrict__ in0, const float* __restrict__ in1, const float* __restrict__ in2,
    float* __restrict__ o0, float* __restrict__ o1, float* __restrict__ o2,
    int R, int C, int rtShift)
{
    __shared__ float tile[32][33];
    const int which = blockIdx.y >> rtShift;
    const int rt    = blockIdx.y & ((1 << rtShift) - 1);
    const float* in = which == 0 ? in0 : (which == 1 ? in1 : in2);
    float*      out = which == 0 ? o0  : (which == 1 ? o1  : o2);
    const size_t boff = (size_t)blockIdx.z * R * C;
    in += boff; out += boff;
    const int tx = threadIdx.x & 31, ty = threadIdx.x >> 5;
    const int r0 = rt * 32, c0 = blockIdx.x * 32;
    #pragma unroll
    for (int j = 0; j < 4; ++j)
        tile[ty + 8*j][tx] = in[(size_t)(r0 + ty + 8*j) * C + c0 + tx];
    __syncthreads();
    #pragma unroll
    for (int j = 0; j < 4; ++j)
        out[(size_t)(c0 + ty + 8*j) * R + r0 + tx] = tile[tx][ty + 8*j];
}

// ---------------- Level 0 (coarse, 16x16) ----------------
// wave handles 4 queries l. Phase A: lane = key-quad, score all 4 l's.
// Phase B: 16-lane group per l: softmax + top-16 (all DPP). Phase C: msg.
__global__ __launch_bounds__(256) void k_lvl0(
    const float* __restrict__ q, const float* __restrict__ k, const float* __restrict__ v,
    float* __restrict__ tscore0, int* __restrict__ tpos0, float* __restrict__ msg0)
{
    const int tid = threadIdx.x, lane = tid & 63, wid = tid >> 6;
    const int l_base = (blockIdx.x * 4 + wid) * 4;   // 4 queries per wave
    const int n = blockIdx.y, b = blockIdx.z;
    const int S = 256;

    // [wave][l_loc][keys, chunk-padded: key -> key + 4*(key>>6)]
    __shared__ float scl[4][4][272];

    // ---- phase A: scores for 4 l x 4 keys per lane ----
    const float* kb = k + ((size_t)(b*128 + n*16))*S + lane*4;
    const float* qb = q + ((size_t)(b*128 + n*16))*S + l_base;
    float sc[4][4] = {};
    #pragma unroll
    for (int dd = 0; dd < 16; ++dd) {
        float4 kv = *(const float4*)(kb + (size_t)dd*S);
        float4 q4 = *(const float4*)(qb + (size_t)dd*S);
        const float qa[4] = {q4.x, q4.y, q4.z, q4.w};
        const float ka[4] = {kv.x, kv.y, kv.z, kv.w};
        #pragma unroll
        for (int lo = 0; lo < 4; ++lo)
            #pragma unroll
            for (int j = 0; j < 4; ++j)
                sc[lo][j] = fmaf(qa[lo], ka[j], sc[lo][j]);
    }
    const int wbase = lane*4 + 4*(lane>>4);
    #pragma unroll
    for (int lo = 0; lo < 4; ++lo) {
        float4 o = make_float4(sc[lo][0]*0.25f, sc[lo][1]*0.25f,
                               sc[lo][2]*0.25f, sc[lo][3]*0.25f);
        *(float4*)&scl[wid][lo][wbase] = o;
    }
    __syncthreads();

    // ---- phase B: group lg handles query l_base+lg; li owns 16 keys ----
    const int lg = lane >> 4, li = lane & 15;
    const int rbase = li*16 + 4*(li>>2);
    float p[16];
    #pragma unroll
    for (int c = 0; c < 4; ++c)
        *(float4*)&p[c*4] = *(const float4*)&scl[wid][lg][rbase + 4*c];

    float m = p[0];
    #pragma unroll
    for (int j = 1; j < 16; ++j) m = fmaxf(m, p[j]);
    m = rowmax16(m);
    float lsum = 0.f;
    #pragma unroll
    for (int j = 0; j < 16; ++j) { p[j] = expf(p[j] - m); lsum += p[j]; }
    const float su = rowsum16(lsum);
    const float inv = 1.f / su;
    #pragma unroll
    for (int j = 0; j < 16; ++j) p[j] *= inv;

    const int l = l_base + lg;
    const int slot_base = li * 16;
    float myv = 0.f; int myslot = 0;
    #pragma unroll 1
    for (int it = 0; it < 16; ++it) {
        float bv = p[0]; int bs = slot_base;
        #pragma unroll
        for (int j = 1; j < 16; ++j)
            if (p[j] > bv) { bv = p[j]; bs = slot_base + j; }
        amax16(bv, bs);
        const bool win = (bs >> 4) == li;
        #pragma unroll
        for (int j = 0; j < 16; ++j)
            p[j] = (win && (bs & 15) == j) ? 0.f : p[j];
        if (li == it) { myv = bv; myslot = bs; }
    }
    {   // every lane li stores extraction #li
        const size_t ob = (((size_t)b*256 + l)*16 + li)*8 + n;
        tscore0[ob] = myv;
        tpos0 [ob] = myslot;
    }
    #pragma unroll
    for (int c = 0; c < 4; ++c)
        *(float4*)&scl[wid][lg][rbase + 4*c] = *(const float4*)&p[c*4];
    __syncthreads();

    // ---- phase C: msg0 = masked-p . V ; lane = (chunk, dd) ----
    const int dd = lane & 15, chunk = lane >> 4;
    const float* vb = v + ((size_t)(b*128 + n*16 + dd))*S + chunk*64;
    float acc[4] = {0.f, 0.f, 0.f, 0.f};
    #pragma unroll
    for (int jj = 0; jj < 16; ++jj) {
        float4 vv = *(const float4*)(vb + jj*4);
        #pragma unroll
        for (int lo = 0; lo < 4; ++lo) {
            float4 pp = *(const float4*)&scl[wid][lo][chunk*68 + jj*4];
            acc[lo] = fmaf(pp.x, vv.x, acc[lo]);
            acc[lo] = fmaf(pp.y, vv.y, acc[lo]);
            acc[lo] = fmaf(pp.z, vv.z, acc[lo]);
            acc[lo] = fmaf(pp.w, vv.w, acc[lo]);
        }
    }
    #pragma unroll
    for (int lo = 0; lo < 4; ++lo) {
        acc[lo] += __shfl_xor(acc[lo], 16);
        acc[lo] += __shfl_xor(acc[lo], 32);
    }
    if (lane < 16) {
        #pragma unroll
        for (int lo = 0; lo < 4; ++lo)
            msg0[(((size_t)b*256 + (l_base + lo))*8 + n)*16 + dd] = acc[lo];
    }
}

// ---------------- Level 1 (fine, 32x32) ----------------
// wave = (b,L,n), L on 16x16 coarse grid; 4 queries t; 64 gathered keys.
__global__ __launch_bounds__(256) void k_lvl1(
    const float* __restrict__ Qt, const float* __restrict__ Kt, const float* __restrict__ Vt,
    const float* __restrict__ tscore0, const int* __restrict__ tpos0,
    float* __restrict__ tscore1, int* __restrict__ tpos1, float* __restrict__ msg1)
{
    const int tid = threadIdx.x, lane = tid & 63, wid = tid >> 6;
    const int L = blockIdx.x;              // 0..255
    const int n = blockIdx.y * 4 + wid;    // 0..7
    const int b = blockIdx.z;

    __shared__ float pl[4][4][68];         // [wave][t][key]

    const int H = L >> 4, W = L & 15;

    // ---- phase A: lane = key kk; score 4 queries ----
    {
        const int kp = lane >> 2, ci = lane & 3;
        const size_t pb = (((size_t)b*256 + L)*16 + kp)*8 + n;
        const int   s      = tpos0[pb];
        const float pscore = tscore0[pb];
        const int g = (((s >> 4)*2 + (ci >> 1)) << 5) + ((s & 15)*2 + (ci & 1));

        const float* kt = Kt + ((size_t)(b*1024 + g)*128 + n*16);
        float kr[16];
        #pragma unroll
        for (int i = 0; i < 4; ++i) *(float4*)&kr[i*4] = *(const float4*)(kt + i*4);

        const float* qhead = Qt + (size_t)b*1024*128 + n*16;
        #pragma unroll
        for (int t = 0; t < 4; ++t) {
            const int qtok = ((2*H + (t>>1)) << 5) + 2*W + (t&1);
            const float* qp = qhead + (size_t)qtok*128;
            float sc = 0.f;
            #pragma unroll
            for (int i = 0; i < 4; ++i) {
                float4 q4 = *(const float4*)(qp + i*4);
                sc = fmaf(q4.x, kr[i*4+0], sc);
                sc = fmaf(q4.y, kr[i*4+1], sc);
                sc = fmaf(q4.z, kr[i*4+2], sc);
                sc = fmaf(q4.w, kr[i*4+3], sc);
            }
            sc *= 0.25f;
            const float mm = quadmax4(sc);
            const float e  = expf(sc - mm);
            const float su = quadsum4(e);
            pl[wid][t][lane] = (e / su) * pscore;
        }
    }
    __syncthreads();

    // ---- phase B: group tg selects top-8 of 64 for query tg (all DPP) ----
    {
        const int tg = lane >> 4, li = lane & 15;
        float p4[4];
        *(float4*)p4 = *(const float4*)&pl[wid][tg][li*4];
        float myv = 0.f; int myslot = 0;
        #pragma unroll 1
        for (int it = 0; it < 8; ++it) {
            float bv = p4[0]; int bs = li*4;
            #pragma unroll
            for (int j = 1; j < 4; ++j)
                if (p4[j] > bv) { bv = p4[j]; bs = li*4 + j; }
            amax16(bv, bs);
            const bool win = (bs >> 2) == li;
            #pragma unroll
            for (int j = 0; j < 4; ++j)
                p4[j] = (win && (bs & 3) == j) ? 0.f : p4[j];
            if (li == it) { myv = bv; myslot = bs; }
        }
        *(float4*)&pl[wid][tg][li*4] = *(const float4*)p4;   // masked write-back
        if (li < 8) {
            const int skp = myslot >> 2, sci = myslot & 3;
            const int s2 = tpos0[(((size_t)b*256 + L)*16 + skp)*8 + n];
            const int gg = (((s2 >> 4)*2 + (sci >> 1)) << 5) + ((s2 & 15)*2 + (sci & 1));
            const int qtok = ((2*H + (tg>>1)) << 5) + 2*W + (tg&1);
            const size_t ob = (((size_t)b*1024 + qtok)*8 + li)*8 + n;
            tscore1[ob] = myv;
            tpos1 [ob] = gg;
        }
    }
    __syncthreads();

    // ---- phase C: msg; lane = (ks, t, dq), V gathered direct from global ----
    {
        const int ks = lane >> 4, t2 = (lane >> 2) & 3, dq = lane & 3;
        int s4[4];
        #pragma unroll
        for (int jj = 0; jj < 4; ++jj)
            s4[jj] = tpos0[(((size_t)b*256 + L)*16 + (ks*4 + jj))*8 + n];
        float4 acc = make_float4(0.f, 0.f, 0.f, 0.f);
        #pragma unroll
        for (int jj = 0; jj < 4; ++jj) {
            float4 pp = *(const float4*)&pl[wid][t2][ks*16 + jj*4];
            const float pa[4] = {pp.x, pp.y, pp.z, pp.w};
            const int sv = s4[jj];
            #pragma unroll
            for (int c = 0; c < 4; ++c) {
                const int gg = (((sv >> 4)*2 + (c >> 1)) << 5) + ((sv & 15)*2 + (c & 1));
                float4 vv = *(const float4*)(Vt + ((size_t)(b*1024 + gg)*128 + n*16 + dq*4));
                acc.x = fmaf(pa[c], vv.x, acc.x);
                acc.y = fmaf(pa[c], vv.y, acc.y);
                acc.z = fmaf(pa[c], vv.z, acc.z);
                acc.w = fmaf(pa[c], vv.w, acc.w);
            }
        }
        acc.x += __shfl_xor(acc.x, 16); acc.y += __shfl_xor(acc.y, 16);
        acc.z += __shfl_xor(acc.z, 16); acc.w += __shfl_xor(acc.w, 16);
        acc.x += __shfl_xor(acc.x, 32); acc.y += __shfl_xor(acc.y, 32);
        acc.z += __shfl_xor(acc.z, 32); acc.w += __shfl_xor(acc.w, 32);
        if (lane < 16) {
            const int qtok = ((2*H + (t2>>1)) << 5) + 2*W + (t2&1);
            *(float4*)(msg1 + (((size_t)b*1024 + qtok)*8 + n)*16 + dq*4) = acc;
        }
    }
}

// ---------------- Level 2 (final, 64x64) + fusion ----------------
// wave = (b,L,n), L on 32x32 grid; 32 gathered keys; no top-k; fused output.
__global__ __launch_bounds__(256) void k_lvl2(
    const float* __restrict__ Qt, const float* __restrict__ Kt, const float* __restrict__ Vt,
    const float* __restrict__ tscore1, const int* __restrict__ tpos1,
    const float* __restrict__ msg0, const float* __restrict__ msg1,
    float* __restrict__ outT)
{
    const int tid = threadIdx.x, lane = tid & 63, wid = tid >> 6;
    const int L = blockIdx.x;              // 0..1023
    const int n = blockIdx.y * 4 + wid;    // 0..7
    const int b = blockIdx.z;

    __shared__ float pl[4][4][36];

    const int H = L >> 5, W = L & 31;

    // ---- phase A: lane = th*32 + kk; each lane scores 2 queries ----
    {
        const int kk = lane & 31, th = lane >> 5;
        const int kp = kk >> 2, ci = kk & 3;
        const size_t pb = (((size_t)b*1024 + L)*8 + kp)*8 + n;
        const int g1 = tpos1[pb];
        const float pscore = tscore1[pb];
        const int g = (((g1 >> 5)*2 + (ci >> 1)) << 6) + ((g1 & 31)*2 + (ci & 1));

        const float* kt = Kt + ((size_t)(b*4096 + g)*128 + n*16);
        float kr[16];
        #pragma unroll
        for (int i = 0; i < 4; ++i) *(float4*)&kr[i*4] = *(const float4*)(kt + i*4);

        const float* qhead = Qt + (size_t)b*4096*128 + n*16;
        #pragma unroll
        for (int tt = 0; tt < 2; ++tt) {
            const int t = th*2 + tt;
            const int qtok = ((2*H + (t>>1)) << 6) + 2*W + (t&1);
            const float* qp = qhead + (size_t)qtok*128;
            float sc = 0.f;
            #pragma unroll
            for (int i = 0; i < 4; ++i) {
                float4 q4 = *(const float4*)(qp + i*4);
                sc = fmaf(q4.x, kr[i*4+0], sc);
                sc = fmaf(q4.y, kr[i*4+1], sc);
                sc = fmaf(q4.z, kr[i*4+2], sc);
                sc = fmaf(q4.w, kr[i*4+3], sc);
            }
            sc *= 0.25f;
            const float mm = quadmax4(sc);
            const float e  = expf(sc - mm);
            const float su = quadsum4(e);
            pl[wid][t][kk] = (e / su) * pscore;
        }
    }
    __syncthreads();

    // ---- phase B: msg + fusion; lane = (ks, t, dq) ----
    {
        const int ks = lane >> 4, t2 = (lane >> 2) & 3, dq = lane & 3;
        int s2[2];
        #pragma unroll
        for (int jj = 0; jj < 2; ++jj)
            s2[jj] = tpos1[(((size_t)b*1024 + L)*8 + (ks*2 + jj))*8 + n];
        float4 acc = make_float4(0.f, 0.f, 0.f, 0.f);
        #pragma unroll
        for (int jj = 0; jj < 2; ++jj) {
            float4 pp = *(const float4*)&pl[wid][t2][ks*8 + jj*4];
            const float pa[4] = {pp.x, pp.y, pp.z, pp.w};
            const int gv = s2[jj];
            #pragma unroll
            for (int c = 0; c < 4; ++c) {
                const int gg = (((gv >> 5)*2 + (c >> 1)) << 6) + ((gv & 31)*2 + (c & 1));
                float4 vv = *(const float4*)(Vt + ((size_t)(b*4096 + gg)*128 + n*16 + dq*4));
                acc.x = fmaf(pa[c], vv.x, acc.x);
                acc.y = fmaf(pa[c], vv.y, acc.y);
                acc.z = fmaf(pa[c], vv.z, acc.z);
                acc.w = fmaf(pa[c], vv.w, acc.w);
            }
        }
        acc.x += __shfl_xor(acc.x, 16); acc.y += __shfl_xor(acc.y, 16);
        acc.z += __shfl_xor(acc.z, 16); acc.w += __shfl_xor(acc.w, 16);
        acc.x += __shfl_xor(acc.x, 32); acc.y += __shfl_xor(acc.y, 32);
        acc.z += __shfl_xor(acc.z, 32); acc.w += __shfl_xor(acc.w, 32);
        if (lane < 16) {
            const int qtok = ((2*H + (t2>>1)) << 6) + 2*W + (t2&1);
            const int l0 = (H >> 1)*16 + (W >> 1);
            float4 m1 = *(const float4*)(msg1 + (((size_t)b*1024 + L)*8 + n)*16 + dq*4);
            float4 m0 = *(const float4*)(msg0 + (((size_t)b*256 + l0)*8 + n)*16 + dq*4);
            acc.x += m1.x + m0.x;
            acc.y += m1.y + m0.y;
            acc.z += m1.z + m0.z;
            acc.w += m1.w + m0.w;
            *(float4*)(outT + ((size_t)b*4096 + qtok)*128 + n*16 + dq*4) = acc;
        }
    }
}

extern "C" void kernel_launch(void* const* d_in, const int* in_sizes, int n_in,
                              void* d_out, int out_size, void* d_ws, size_t ws_size,
                              hipStream_t stream)
{
    const float* q0 = (const float*)d_in[0];
    const float* k0 = (const float*)d_in[1];
    const float* v0 = (const float*)d_in[2];
    const float* q1 = (const float*)d_in[3];
    const float* k1 = (const float*)d_in[4];
    const float* v1 = (const float*)d_in[5];
    const float* q2 = (const float*)d_in[6];
    const float* k2 = (const float*)d_in[7];
    const float* v2 = (const float*)d_in[8];

    float* ws = (float*)d_ws;
    float* tscore0 = ws;                        // 131072
    int*   tpos0   = (int*)(ws + 131072);       // 131072
    float* msg0    = ws + 262144;               // 131072
    float* tscore1 = ws + 393216;               // 262144
    int*   tpos1   = (int*)(ws + 655360);       // 262144
    float* msg1    = ws + 917504;               // 524288
    float* q1t     = ws + 1441792;              // 524288
    float* k1t     = ws + 1966080;              // 524288
    float* v1t     = ws + 2490368;              // 524288
    float* q2t     = ws + 3014656;              // 2097152
    float* k2t     = ws + 5111808;              // 2097152
    float* v2t     = ws + 7208960;              // 2097152
    float* outT    = ws + 9306112;              // 2097152

    // token-major transposes: [128][S] -> [S][128]
    k_xpose3<<<dim3(32,  12, 4), 256, 0, stream>>>(q1, k1, v1, q1t, k1t, v1t, 128, 1024, 2);
    k_xpose3<<<dim3(128, 12, 4), 256, 0, stream>>>(q2, k2, v2, q2t, k2t, v2t, 128, 4096, 2);

    k_lvl0<<<dim3(16,   8, 4), 256, 0, stream>>>(q0, k0, v0, tscore0, tpos0, msg0);
    k_lvl1<<<dim3(256,  2, 4), 256, 0, stream>>>(q1t, k1t, v1t, tscore0, tpos0, tscore1, tpos1, msg1);
    k_lvl2<<<dim3(1024, 2, 4), 256, 0, stream>>>(q2t, k2t, v2t, tscore1, tpos1, msg0, msg1, outT);

    // outT [4096][128] -> out [128][4096]
    k_xpose3<<<dim3(4, 128, 4), 256, 0, stream>>>(outT, outT, outT,
                                                  (float*)d_out, (float*)d_out, (float*)d_out,
                                                  4096, 128, 7);
}

// Round 4
// 164.133 us; speedup vs baseline: 1.6825x; 1.0296x over previous
//
#include <hip/hip_runtime.h>
#include <cstddef>

// QuadTree attention, 3 levels. B=4, C=128, NHEAD=8, d=16.
// Grids: 16x16 (S=256), 32x32 (S=1024), 64x64 (S=4096). TOPKS=(16,8,8).
//
// R4: ONE fused kernel. wave = (b, coarse cell l0, head n) processes the
// whole subtree: lvl0 (256-key softmax, top-16, msg0) -> lvl1 (4 queries x
// 64 gathered keys, top-8, msg1) -> lvl2 (16 queries x 32 keys) -> fused
// 4x4 output patch written channel-major. No intermediate global arrays,
// no __syncthreads (single-wave LDS regroups), 2 launches total.

#define DPP_QUAD_X1 0xB1
#define DPP_QUAD_X2 0x4E
#define DPP_ROR_1   0x121
#define DPP_ROR_2   0x122
#define DPP_ROR_4   0x124
#define DPP_ROR_8   0x128

template<int C>
__device__ __forceinline__ int dpp_i(int x) {
    return __builtin_amdgcn_mov_dpp(x, C, 0xF, 0xF, true);
}
template<int C>
__device__ __forceinline__ float dpp_f(float x) {
    return __int_as_float(__builtin_amdgcn_mov_dpp(__float_as_int(x), C, 0xF, 0xF, true));
}
__device__ __forceinline__ float quadmax4(float x) {
    x = fmaxf(x, dpp_f<DPP_QUAD_X1>(x));
    x = fmaxf(x, dpp_f<DPP_QUAD_X2>(x));
    return x;
}
__device__ __forceinline__ float quadsum4(float x) {
    x += dpp_f<DPP_QUAD_X1>(x);
    x += dpp_f<DPP_QUAD_X2>(x);
    return x;
}
template<int C>
__device__ __forceinline__ void amax_step(float& v, int& s) {
    float ov = dpp_f<C>(v);
    int   os = dpp_i<C>(s);
    const bool take = (ov > v) || (ov == v && os < s);
    v = take ? ov : v;
    s = take ? os : s;
}
__device__ __forceinline__ void amax16(float& v, int& s) {
    amax_step<DPP_ROR_1>(v, s);
    amax_step<DPP_ROR_2>(v, s);
    amax_step<DPP_ROR_4>(v, s);
    amax_step<DPP_ROR_8>(v, s);
}
// full-wave argmax: DPP rows then cross-row shuffles
__device__ __forceinline__ void amax64(float& v, int& s) {
    amax16(v, s);
    {   float ov = __shfl_xor(v, 16); int os = __shfl_xor(s, 16);
        const bool t = (ov > v) || (ov == v && os < s); v = t ? ov : v; s = t ? os : s; }
    {   float ov = __shfl_xor(v, 32); int os = __shfl_xor(s, 32);
        const bool t = (ov > v) || (ov == v && os < s); v = t ? ov : v; s = t ? os : s; }
}
__device__ __forceinline__ float wavemax(float x) {
    x = fmaxf(x, dpp_f<DPP_ROR_1>(x)); x = fmaxf(x, dpp_f<DPP_ROR_2>(x));
    x = fmaxf(x, dpp_f<DPP_ROR_4>(x)); x = fmaxf(x, dpp_f<DPP_ROR_8>(x));
    x = fmaxf(x, __shfl_xor(x, 16));   x = fmaxf(x, __shfl_xor(x, 32));
    return x;
}
__device__ __forceinline__ float wavesum(float x) {
    x += dpp_f<DPP_ROR_1>(x); x += dpp_f<DPP_ROR_2>(x);
    x += dpp_f<DPP_ROR_4>(x); x += dpp_f<DPP_ROR_8>(x);
    x += __shfl_xor(x, 16);   x += __shfl_xor(x, 32);
    return x;
}
__device__ __forceinline__ float dot16(const float* __restrict__ qp, const float* kr) {
    float s = 0.f;
    #pragma unroll
    for (int i = 0; i < 4; ++i) {
        float4 a = *(const float4*)(qp + i*4);
        s = fmaf(a.x, kr[i*4+0], s);
        s = fmaf(a.y, kr[i*4+1], s);
        s = fmaf(a.z, kr[i*4+2], s);
        s = fmaf(a.w, kr[i*4+3], s);
    }
    return s;
}

// ---------------- Fused input transpose: 6 tensors [128][S] -> [S][128] ---
// bx<384: lvl1 q/k/v (S=1024); else lvl2 q/k/v (S=4096). 32x32 tiles.
__global__ __launch_bounds__(256) void k_xpose(
    const float* __restrict__ i0, const float* __restrict__ i1, const float* __restrict__ i2,
    const float* __restrict__ i3, const float* __restrict__ i4, const float* __restrict__ i5,
    float* __restrict__ o0, float* __restrict__ o1, float* __restrict__ o2,
    float* __restrict__ o3, float* __restrict__ o4, float* __restrict__ o5)
{
    __shared__ float tile[32][33];
    const int bx = blockIdx.x;
    int t, rt, ct, C;
    if (bx < 384) { t = bx >> 7;            int r = bx & 127; rt = r >> 5; ct = r & 31;  C = 1024; }
    else          { t = 3 + ((bx-384) >> 9); int r = bx & 511; rt = r >> 7; ct = r & 127; C = 4096; }
    const float* in;  float* out;
    switch (t) {
        case 0: in = i0; out = o0; break;  case 1: in = i1; out = o1; break;
        case 2: in = i2; out = o2; break;  case 3: in = i3; out = o3; break;
        case 4: in = i4; out = o4; break;  default: in = i5; out = o5; break;
    }
    const size_t boff = (size_t)blockIdx.z * 128 * C;
    in += boff; out += boff;
    const int tx = threadIdx.x & 31, ty = threadIdx.x >> 5;
    const int r0 = rt * 32, c0 = ct * 32;
    #pragma unroll
    for (int j = 0; j < 4; ++j)
        tile[ty + 8*j][tx] = in[(size_t)(r0 + ty + 8*j) * C + c0 + tx];
    __syncthreads();
    #pragma unroll
    for (int j = 0; j < 4; ++j)
        out[(size_t)(c0 + ty + 8*j) * 128 + r0 + tx] = tile[tx][ty + 8*j];
}

// ---------------- Fused 3-level subtree kernel ----------------
// grid (256, 2, 4) x 256 threads; wave = (b, l0, n = blockIdx.y*4+wid).
// Arena per wave (floats):
//   [0..287]    lvl0 p (chunk-padded 272) / lvl2 pl2 [t1l][t2][36]
//   [288..559]  lvl1 pl [t][68]           / out tile [16q][16dd]
//   [560..575]  msg0 [16dd]
//   [576..639]  msg1 [4t1][16dd]
__global__ __launch_bounds__(256) void k_fused(
    const float* __restrict__ q0, const float* __restrict__ k0, const float* __restrict__ v0,
    const float* __restrict__ Q1, const float* __restrict__ K1, const float* __restrict__ V1,
    const float* __restrict__ Q2, const float* __restrict__ K2, const float* __restrict__ V2,
    float* __restrict__ out)
{
    const int tid = threadIdx.x, lane = tid & 63, wid = tid >> 6;
    const int l0 = blockIdx.x;             // 0..255
    const int n  = blockIdx.y * 4 + wid;   // 0..7
    const int b  = blockIdx.z;             // 0..3
    const int H0 = l0 >> 4, W0 = l0 & 15;

    __shared__ float arenaAll[4][640];
    __shared__ int   gl2All[4][64];
    float* A = arenaAll[wid];
    int*   G = gl2All[wid];

    // ======== stage A: lvl0 scores (channel-major q0/k0/v0) ========
    const float* qb = q0 + ((size_t)(b*128 + n*16))*256 + l0;
    const float* kb = k0 + ((size_t)(b*128 + n*16))*256 + lane*4;
    float qreg[16];
    #pragma unroll
    for (int dd = 0; dd < 16; ++dd) qreg[dd] = qb[(size_t)dd*256];
    float p[4] = {0.f, 0.f, 0.f, 0.f};
    #pragma unroll
    for (int dd = 0; dd < 16; ++dd) {
        float4 kv = *(const float4*)(kb + (size_t)dd*256);
        p[0] = fmaf(qreg[dd], kv.x, p[0]);
        p[1] = fmaf(qreg[dd], kv.y, p[1]);
        p[2] = fmaf(qreg[dd], kv.z, p[2]);
        p[3] = fmaf(qreg[dd], kv.w, p[3]);
    }
    #pragma unroll
    for (int j = 0; j < 4; ++j) p[j] *= 0.25f;
    // wave softmax over 256
    float m = fmaxf(fmaxf(p[0], p[1]), fmaxf(p[2], p[3]));
    m = wavemax(m);
    float ls = 0.f;
    #pragma unroll
    for (int j = 0; j < 4; ++j) { p[j] = expf(p[j] - m); ls += p[j]; }
    const float inv = 1.f / wavesum(ls);
    #pragma unroll
    for (int j = 0; j < 4; ++j) p[j] *= inv;

    // ======== stage B: top-16 of 256 (winners zeroed == mask) ========
    float myv0 = 0.f; int mypos0 = 0;
    #pragma unroll 1
    for (int it = 0; it < 16; ++it) {
        float lv = p[0]; int li = 0;
        if (p[1] > lv) { lv = p[1]; li = 1; }
        if (p[2] > lv) { lv = p[2]; li = 2; }
        if (p[3] > lv) { lv = p[3]; li = 3; }
        int gi = (lane << 2) | li;
        amax64(lv, gi);
        const bool win = (gi >> 2) == lane;
        #pragma unroll
        for (int j = 0; j < 4; ++j)
            p[j] = (win && (gi & 3) == j) ? 0.f : p[j];
        if (lane == it) { myv0 = lv; mypos0 = gi; }
    }

    // ======== stage C: msg0 = masked-p . V0 ========
    *(float4*)&A[lane*4 + 4*(lane>>4)] = make_float4(p[0], p[1], p[2], p[3]);
    {
        const int dd = lane & 15, chunk = lane >> 4;
        const float* vb = v0 + ((size_t)(b*128 + n*16 + dd))*256 + chunk*64;
        float acc = 0.f;
        #pragma unroll
        for (int jj = 0; jj < 16; ++jj) {
            float4 vv = *(const float4*)(vb + jj*4);
            float4 pp = *(const float4*)&A[chunk*68 + jj*4];
            acc = fmaf(pp.x, vv.x, acc);
            acc = fmaf(pp.y, vv.y, acc);
            acc = fmaf(pp.z, vv.z, acc);
            acc = fmaf(pp.w, vv.w, acc);
        }
        acc += __shfl_xor(acc, 16);
        acc += __shfl_xor(acc, 32);
        if (lane < 16) A[560 + dd] = acc;
    }

    // ======== stage D: lvl1 scoring + top-8 per query ========
    {
        const int kp = lane >> 2, ci = lane & 3;
        const float pscore = __shfl(myv0, kp);
        const int   spos   = __shfl(mypos0, kp);
        const int g1 = (((spos >> 4)*2 + (ci >> 1)) << 5) + ((spos & 15)*2 + (ci & 1));
        const float* kt = K1 + ((size_t)(b*1024 + g1)*128 + n*16);
        float kr[16];
        #pragma unroll
        for (int i = 0; i < 4; ++i) *(float4*)&kr[i*4] = *(const float4*)(kt + i*4);
        #pragma unroll
        for (int t = 0; t < 4; ++t) {
            const int qtok = ((2*H0 + (t>>1)) << 5) + 2*W0 + (t&1);
            float sc = dot16(Q1 + ((size_t)(b*1024 + qtok)*128 + n*16), kr) * 0.25f;
            const float mm = quadmax4(sc);
            const float e  = expf(sc - mm);
            const float su = quadsum4(e);
            A[288 + t*68 + lane] = (e / su) * pscore;
        }
    }
    float myv1 = 0.f; int myg1 = 0;
    {
        const int tg = lane >> 4, li = lane & 15;
        float p4[4];
        *(float4*)p4 = *(const float4*)&A[288 + tg*68 + li*4];
        int myslot = 0;
        #pragma unroll 1
        for (int it = 0; it < 8; ++it) {
            float bv = p4[0]; int bs = li*4;
            if (p4[1] > bv) { bv = p4[1]; bs = li*4 + 1; }
            if (p4[2] > bv) { bv = p4[2]; bs = li*4 + 2; }
            if (p4[3] > bv) { bv = p4[3]; bs = li*4 + 3; }
            amax16(bv, bs);
            const bool win = (bs >> 2) == li;
            #pragma unroll
            for (int j = 0; j < 4; ++j)
                p4[j] = (win && (bs & 3) == j) ? 0.f : p4[j];
            if (li == it) { myv1 = bv; myslot = bs; }
        }
        *(float4*)&A[288 + tg*68 + li*4] = *(const float4*)p4;   // masked write-back
        const int sp2 = __shfl(mypos0, myslot >> 2);
        const int sci = myslot & 3;
        myg1 = (((sp2 >> 4)*2 + (sci >> 1)) << 5) + ((sp2 & 15)*2 + (sci & 1));
    }

    // ======== stage E: msg1 (V1 gathered direct) ========
    {
        const int ks = lane >> 4, t2 = (lane >> 2) & 3, dq = lane & 3;
        float4 acc = make_float4(0.f, 0.f, 0.f, 0.f);
        #pragma unroll
        for (int jj = 0; jj < 4; ++jj) {
            const int pp = __shfl(mypos0, ks*4 + jj);
            float4 pv = *(const float4*)&A[288 + t2*68 + ks*16 + jj*4];
            const float pa[4] = {pv.x, pv.y, pv.z, pv.w};
            #pragma unroll
            for (int c = 0; c < 4; ++c) {
                const int g = (((pp >> 4)*2 + (c >> 1)) << 5) + ((pp & 15)*2 + (c & 1));
                float4 vv = *(const float4*)(V1 + ((size_t)(b*1024 + g)*128 + n*16 + dq*4));
                acc.x = fmaf(pa[c], vv.x, acc.x);
                acc.y = fmaf(pa[c], vv.y, acc.y);
                acc.z = fmaf(pa[c], vv.z, acc.z);
                acc.w = fmaf(pa[c], vv.w, acc.w);
            }
        }
        acc.x += __shfl_xor(acc.x, 16); acc.y += __shfl_xor(acc.y, 16);
        acc.z += __shfl_xor(acc.z, 16); acc.w += __shfl_xor(acc.w, 16);
        acc.x += __shfl_xor(acc.x, 32); acc.y += __shfl_xor(acc.y, 32);
        acc.z += __shfl_xor(acc.z, 32); acc.w += __shfl_xor(acc.w, 32);
        if (lane < 16)
            *(float4*)&A[576 + t2*16 + dq*4] = acc;
    }

    // ======== stage F: lvl2 (two passes of 2 t1-groups) + fusion ========
    #pragma unroll 1
    for (int hp = 0; hp < 2; ++hp) {
        // score phase: lane = (t1l = lane>>5, kk = lane&31)
        {
            const int t1l = lane >> 5, kk = lane & 31;
            const int t1 = hp*2 + t1l;
            const int kp2 = kk >> 2, ci2 = kk & 3;
            const float ps1 = __shfl(myv1, t1*16 + kp2);
            const int   g1s = __shfl(myg1, t1*16 + kp2);
            const int g2 = (((g1s >> 5)*2 + (ci2 >> 1)) << 6) + ((g1s & 31)*2 + (ci2 & 1));
            G[t1l*32 + kk] = g2;
            const float* kt = K2 + ((size_t)(b*4096 + g2)*128 + n*16);
            float kr[16];
            #pragma unroll
            for (int i = 0; i < 4; ++i) *(float4*)&kr[i*4] = *(const float4*)(kt + i*4);
            const int y1 = 2*H0 + (t1 >> 1), x1 = 2*W0 + (t1 & 1);
            #pragma unroll
            for (int t2 = 0; t2 < 4; ++t2) {
                const int qtok2 = ((2*y1 + (t2>>1)) << 6) + 2*x1 + (t2&1);
                float sc = dot16(Q2 + ((size_t)(b*4096 + qtok2)*128 + n*16), kr) * 0.25f;
                const float mm = quadmax4(sc);
                const float e  = expf(sc - mm);
                const float su = quadsum4(e);
                A[t1l*144 + t2*36 + kk] = (e / su) * ps1;
            }
        }
        // msg phase: lane = (ks2 = lane>>5, qq = (lane>>2)&7, dq = lane&3)
        {
            const int ks2 = lane >> 5, qq = (lane >> 2) & 7, dq = lane & 3;
            const int t1l = qq >> 2, t2 = qq & 3;
            const int t1 = hp*2 + t1l;
            float4 acc = make_float4(0.f, 0.f, 0.f, 0.f);
            #pragma unroll
            for (int j4 = 0; j4 < 4; ++j4) {
                float4 pv = *(const float4*)&A[t1l*144 + t2*36 + ks2*16 + j4*4];
                const float pa[4] = {pv.x, pv.y, pv.z, pv.w};
                #pragma unroll
                for (int c = 0; c < 4; ++c) {
                    const int gv = G[t1l*32 + ks2*16 + j4*4 + c];
                    float4 vv = *(const float4*)(V2 + ((size_t)(b*4096 + gv)*128 + n*16 + dq*4));
                    acc.x = fmaf(pa[c], vv.x, acc.x);
                    acc.y = fmaf(pa[c], vv.y, acc.y);
                    acc.z = fmaf(pa[c], vv.z, acc.z);
                    acc.w = fmaf(pa[c], vv.w, acc.w);
                }
            }
            acc.x += __shfl_xor(acc.x, 32); acc.y += __shfl_xor(acc.y, 32);
            acc.z += __shfl_xor(acc.z, 32); acc.w += __shfl_xor(acc.w, 32);
            if (lane < 32) {
                float4 m1 = *(const float4*)&A[576 + t1*16 + dq*4];
                float4 m0 = *(const float4*)&A[560 + dq*4];
                acc.x += m1.x + m0.x;
                acc.y += m1.y + m0.y;
                acc.z += m1.z + m0.z;
                acc.w += m1.w + m0.w;
                *(float4*)&A[288 + (t1*4 + t2)*16 + dq*4] = acc;   // out tile
            }
        }
    }

    // ======== output: channel-major 4x4 patch ========
    {
        const int y = lane & 3, dd = lane >> 2;    // dd in [0,16)
        float vr[4];
        #pragma unroll
        for (int x = 0; x < 4; ++x) {
            const int t1 = (((y>>1) << 1) | (x>>1));
            const int t2 = (((y&1)  << 1) | (x&1));
            vr[x] = A[288 + (t1*4 + t2)*16 + dd];
        }
        float* op = out + (((size_t)(b*128 + n*16 + dd)*64 + 4*H0 + y))*64 + 4*W0;
        *(float4*)op = make_float4(vr[0], vr[1], vr[2], vr[3]);
    }
}

extern "C" void kernel_launch(void* const* d_in, const int* in_sizes, int n_in,
                              void* d_out, int out_size, void* d_ws, size_t ws_size,
                              hipStream_t stream)
{
    const float* q0 = (const float*)d_in[0];
    const float* k0 = (const float*)d_in[1];
    const float* v0 = (const float*)d_in[2];
    const float* q1 = (const float*)d_in[3];
    const float* k1 = (const float*)d_in[4];
    const float* v1 = (const float*)d_in[5];
    const float* q2 = (const float*)d_in[6];
    const float* k2 = (const float*)d_in[7];
    const float* v2 = (const float*)d_in[8];

    float* ws = (float*)d_ws;
    float* q1t = ws;                 // 4*1024*128 = 524288
    float* k1t = ws + 524288;
    float* v1t = ws + 1048576;
    float* q2t = ws + 1572864;       // 4*4096*128 = 2097152
    float* k2t = ws + 3670016;
    float* v2t = ws + 5767168;

    k_xpose<<<dim3(1920, 1, 4), 256, 0, stream>>>(q1, k1, v1, q2, k2, v2,
                                                  q1t, k1t, v1t, q2t, k2t, v2t);
    k_fused<<<dim3(256, 2, 4), 256, 0, stream>>>(q0, k0, v0,
                                                 q1t, k1t, v1t,
                                                 q2t, k2t, v2t,
                                                 (float*)d_out);
}